// Round 13
// baseline (334.450 us; speedup 1.0000x reference)
//
#include <hip/hip_runtime.h>
#include <math.h>

#define D 256
#define NX 16
#define L 2048
#define NBATCH 8
#define NTOK (NBATCH * L)
#define CL 16
#define NCH (L / CL)  // 128
#define LOG2E 1.44269504088896340736f

// ---------------- K0: At[n][d] = A[d][n]*LOG2E ; Wbct[d][c] = [WB;WC]^T -----
__global__ __launch_bounds__(256) void k0_prep(const float* __restrict__ A,
                                               const float* __restrict__ WB,
                                               const float* __restrict__ WC,
                                               float* __restrict__ At,
                                               float* __restrict__ Wbct) {
  int i = blockIdx.x * 256 + threadIdx.x;  // 12288 total
  if (i < 4096) {
    int d = i >> 4, n = i & 15;
    At[n * D + d] = A[i] * LOG2E;
  } else {
    int j = i - 4096;  // 8192
    int d = j >> 5, c = j & 31;
    Wbct[j] = (c < 16) ? WB[c * D + d] : WC[(c - 16) * D + d];
  }
}

// ---------------- K1a: 16-token front end + local chunk scan ----------------
// 1024 blocks -> 4+ blocks/CU. Wave owns 4 tokens in phase A.
__global__ __launch_bounds__(256, 4) void k1a_front_scan(
    const float* __restrict__ y, const float* __restrict__ Win,
    const float* __restrict__ bin_, const float* __restrict__ ng,
    const float* __restrict__ nb, const float* __restrict__ Wbct,
    const float* __restrict__ qd, const float* __restrict__ pd,
    const float* __restrict__ At,
    float* __restrict__ hn, float* __restrict__ delta,
    float* __restrict__ Bm, float* __restrict__ Cm,
    float* __restrict__ muv, float* __restrict__ irsv,
    float* __restrict__ EX, float* __restrict__ T) {
  __shared__ float sy[CL][32];     // 2 KB
  __shared__ float sh[CL][260];    // 16.6 KB
  __shared__ float sB[CL][NX];     // 1 KB
  __shared__ float sdelta[CL];
  int t = threadIdx.x;
  int tok0 = blockIdx.x * CL;
  if (t < 128) {
    ((float4*)sy)[t] = ((const float4*)(y + (size_t)tok0 * 32))[t];
  }
  __syncthreads();
  int dcol = t & 63;
  int jrow = t >> 6;
  int d4 = dcol * 4, j4 = jrow * 4;
  float4 bv = ((const float4*)bin_)[dcol];
  float4 acc[4];
  #pragma unroll
  for (int jj = 0; jj < 4; ++jj) acc[jj] = bv;
  const float4* Win4 = (const float4*)Win;  // [k][64 float4]
  #pragma unroll
  for (int k = 0; k < 32; ++k) {
    float4 wv = Win4[k * 64 + dcol];
    #pragma unroll
    for (int jj = 0; jj < 4; ++jj) {
      float av = sy[j4 + jj][k];  // wave-uniform broadcast
      acc[jj].x = fmaf(av, wv.x, acc[jj].x);
      acc[jj].y = fmaf(av, wv.y, acc[jj].y);
      acc[jj].z = fmaf(av, wv.z, acc[jj].z);
      acc[jj].w = fmaf(av, wv.w, acc[jj].w);
    }
  }
  float4 g4 = ((const float4*)ng)[dcol];
  float4 nb4 = ((const float4*)nb)[dcol];
  float4 q4 = ((const float4*)qd)[dcol];
  float pd0 = pd[0];
  #pragma unroll
  for (int jj = 0; jj < 4; ++jj) {
    int j = j4 + jj;
    int tok = tok0 + j;
    float4 a = acc[jj];
    float s1 = a.x + a.y + a.z + a.w;
    float s2 = a.x * a.x + a.y * a.y + a.z * a.z + a.w * a.w;
    #pragma unroll
    for (int off = 1; off < 64; off <<= 1) {
      s1 += __shfl_xor(s1, off);
      s2 += __shfl_xor(s2, off);
    }
    float mu = s1 * (1.f / D);
    float var = s2 * (1.f / D) - mu * mu;
    float rstd = rsqrtf(var + 1e-5f);
    if (dcol == 0) { muv[tok] = mu; irsv[tok] = sqrtf(var + 1e-5f); }
    float4 v4;
    v4.x = (a.x - mu) * rstd * g4.x + nb4.x;
    v4.y = (a.y - mu) * rstd * g4.y + nb4.y;
    v4.z = (a.z - mu) * rstd * g4.z + nb4.z;
    v4.w = (a.w - mu) * rstd * g4.w + nb4.w;
    ((float4*)(hn + (size_t)tok * D))[dcol] = v4;
    *(float4*)&sh[j][d4] = v4;
    float dd = v4.x * q4.x + v4.y * q4.y + v4.z * q4.z + v4.w * q4.w;
    #pragma unroll
    for (int off = 1; off < 64; off <<= 1) dd += __shfl_xor(dd, off);
    if (dcol == 0) {
      float xx = pd0 + dd;
      float dv = (xx > 20.f) ? xx : log1pf(expf(xx));
      delta[tok] = dv;
      sdelta[j] = dv;
    }
  }
  __syncthreads();
  if (t < CL) {  // chunk delta total (lanes 0..15, wave 0)
    float v = sdelta[t];
    #pragma unroll
    for (int off = 1; off < CL; off <<= 1) v += __shfl_xor(v, off);
    if (t == 0) T[blockIdx.x] = v;
  }
  // Phase C: [Bm|Cm](16 tok x 32 cols) = sh @ Wbct; thread = (token, 2 cols)
  int j = t >> 4, c = t & 15;
  const float2* Wb2 = (const float2*)Wbct;  // [d][16 float2]
  float2 o = make_float2(0.f, 0.f);
  #pragma unroll 8
  for (int d = 0; d < 256; ++d) {
    float av = sh[j][d];          // 4-way broadcast per wave
    float2 w = Wb2[d * 16 + c];
    o.x = fmaf(av, w.x, o.x);
    o.y = fmaf(av, w.y, o.y);
  }
  int tokj = tok0 + j;
  int col = c * 2;
  if (col < 16) {
    *(float2*)&Bm[(size_t)tokj * NX + col] = o;
    *(float2*)&sB[j][col] = o;
  } else {
    *(float2*)&Cm[(size_t)tokj * NX + col - 16] = o;
  }
  __syncthreads();
  // local scan, zero init; thread = d
  float a16[16];
  #pragma unroll
  for (int n = 0; n < 16; ++n) a16[n] = At[n * D + t];
  float x16[16];
  #pragma unroll
  for (int n = 0; n < 16; ++n) x16[n] = 0.f;
  for (int lo = 0; lo < CL; ++lo) {
    float dlt = sdelta[lo];
    float du = dlt * sh[lo][t];
    #pragma unroll
    for (int n = 0; n < 16; ++n)
      x16[n] = fmaf(exp2f(dlt * a16[n]), x16[n], du * sB[lo][n]);
  }
  size_t exbase = (size_t)blockIdx.x * (NX * D) + t;
  #pragma unroll
  for (int n = 0; n < 16; ++n) EX[exbase + n * D] = x16[n];
}

// ---------------- K2b: chunk-level scan over 128 chunks ---------------------
__global__ __launch_bounds__(256) void k2b_chunkscan(
    const float* __restrict__ At, const float* __restrict__ T,
    float* __restrict__ EX) {
  __shared__ float sT[NCH];
  int b = blockIdx.x >> 4;
  int rem = ((blockIdx.x & 15) << 8) | threadIdx.x;  // n*D + d
  if (threadIdx.x < NCH) sT[threadIdx.x] = T[b * NCH + threadIdx.x];
  __syncthreads();
  float A2 = At[rem];
  size_t base = ((size_t)b << 19) + rem;  // b*NCH*4096
  float eq[4];
  #pragma unroll
  for (int j = 0; j < 4; ++j) eq[j] = EX[base + ((size_t)j << 12)];
  float x = 0.f;
  #pragma unroll 4
  for (int c = 0; c < NCH; ++c) {
    float e = eq[c & 3];
    if (c + 4 < NCH) eq[c & 3] = EX[base + ((size_t)(c + 4) << 12)];
    EX[base + ((size_t)c << 12)] = x;
    x = fmaf(exp2f(sT[c] * A2), x, e);
  }
}

__device__ __forceinline__ float gelu_exact(float x) {
  return 0.5f * x * (1.f + erff(x * 0.70710678118654752440f));
}

#define FMA4(AV, JJ)                          \
  acc[JJ].x = fmaf(AV, w.x, acc[JJ].x);       \
  acc[JJ].y = fmaf(AV, w.y, acc[JJ].y);       \
  acc[JJ].z = fmaf(AV, w.z, acc[JJ].z);       \
  acc[JJ].w = fmaf(AV, w.w, acc[JJ].w);

// ---------------- K2cd: scan + LN2 + MLP, 16-token tile, 4 blocks/CU --------
__global__ __launch_bounds__(256, 4) void k2cd_scan_mlp(
    const float* __restrict__ hn, const float* __restrict__ delta,
    const float* __restrict__ Bm, const float* __restrict__ Cm,
    const float* __restrict__ At, const float* __restrict__ EX,
    const float* __restrict__ muv, const float* __restrict__ irsv,
    const float* __restrict__ ng, const float* __restrict__ nb,
    const float* __restrict__ nfg, const float* __restrict__ nfb,
    const float* __restrict__ W1, const float* __restrict__ b1,
    const float* __restrict__ W2, const float* __restrict__ b2,
    float* __restrict__ out) {
  __shared__ float s_a[256 * 20];   // aT[d][tok], pitch 20 (20 KB); later z[16][260]
  __shared__ float s_w[16 * 256];   // 16-row W1 k-tile (16 KB)
  __shared__ float sB[CL][NX];
  __shared__ float sC[CL][NX];
  __shared__ float sdelta[CL];
  __shared__ float smu[CL];
  __shared__ float sirs[CL];
  int t = threadIdx.x;
  int tok0 = blockIdx.x * CL;
  size_t tokbase = (size_t)tok0;
  if (t < CL) {
    sdelta[t] = delta[tokbase + t];
    smu[t] = muv[tokbase + t];
    sirs[t] = irsv[tokbase + t];
  }
  ((float*)sB)[t] = Bm[tokbase * NX + t];  // 16*16 = 256 exactly
  ((float*)sC)[t] = Cm[tokbase * NX + t];
  float a16[16], x16[16];
  size_t exbase = (size_t)blockIdx.x * (NX * D) + t;
  #pragma unroll
  for (int n = 0; n < 16; ++n) {
    a16[n] = At[n * D + t];
    x16[n] = EX[exbase + n * D];
  }
  float nb_d = nb[t];
  float invg = 1.0f / ng[t];
  __syncthreads();
  // fixup scan with true entering state -> transposed tile aT[d][lo]
  for (int lo = 0; lo < CL; ++lo) {
    float hv = hn[(tokbase + lo) * D + t];
    float dlt = sdelta[lo];
    float du = dlt * hv;
    float p = 0.f;
    #pragma unroll
    for (int n = 0; n < 16; ++n) {
      x16[n] = fmaf(exp2f(dlt * a16[n]), x16[n], du * sB[lo][n]);
      p = fmaf(x16[n], sC[lo][n], p);
    }
    float h = fmaf((hv - nb_d) * invg, sirs[lo], smu[lo]);
    s_a[t * 20 + lo] = h + p;
  }
  __syncthreads();
  int dcol = t & 63, jrow = t >> 6;
  int d4 = dcol * 4, j4 = jrow * 4;
  // LN2 over aT columns: wave jrow owns tokens j4..j4+3; lane owns 4 d's
  {
    float g0 = nfg[dcol], g1 = nfg[dcol + 64], g2 = nfg[dcol + 128], g3 = nfg[dcol + 192];
    float c0 = nfb[dcol], c1 = nfb[dcol + 64], c2 = nfb[dcol + 128], c3 = nfb[dcol + 192];
    #pragma unroll
    for (int jj = 0; jj < 4; ++jj) {
      int lo = j4 + jj;
      float v0 = s_a[dcol * 20 + lo];
      float v1 = s_a[(dcol + 64) * 20 + lo];
      float v2 = s_a[(dcol + 128) * 20 + lo];
      float v3 = s_a[(dcol + 192) * 20 + lo];
      float s1 = v0 + v1 + v2 + v3;
      float s2 = v0 * v0 + v1 * v1 + v2 * v2 + v3 * v3;
      #pragma unroll
      for (int off = 1; off < 64; off <<= 1) {
        s1 += __shfl_xor(s1, off);
        s2 += __shfl_xor(s2, off);
      }
      float mu2 = s1 * (1.f / D);
      float var2 = s2 * (1.f / D) - mu2 * mu2;
      float rstd2 = rsqrtf(var2 + 1e-5f);
      s_a[dcol * 20 + lo]         = (v0 - mu2) * rstd2 * g0 + c0;
      s_a[(dcol + 64) * 20 + lo]  = (v1 - mu2) * rstd2 * g1 + c1;
      s_a[(dcol + 128) * 20 + lo] = (v2 - mu2) * rstd2 * g2 + c2;
      s_a[(dcol + 192) * 20 + lo] = (v3 - mu2) * rstd2 * g3 + c3;
    }
  }
  // W1 GEMM: 16 k-tiles of 16 rows; a-operand = 1 wave-uniform b128 per k
  float4 acc[4];
  #pragma unroll
  for (int jj = 0; jj < 4; ++jj) acc[jj] = make_float4(0.f, 0.f, 0.f, 0.f);
  const float4* W1g = (const float4*)W1;
  float4* s_w4 = (float4*)s_w;
  for (int kt = 0; kt < 16; ++kt) {
    __syncthreads();  // prior tile reads done (first: LN2 writes visible)
    #pragma unroll
    for (int i = 0; i < 4; ++i) s_w4[t + 256 * i] = W1g[kt * 1024 + t + 256 * i];
    __syncthreads();
    #pragma unroll
    for (int k = 0; k < 16; ++k) {
      float4 w = s_w4[k * 64 + dcol];                       // stride-1 b128
      float4 a4 = *(float4*)&s_a[(kt * 16 + k) * 20 + j4];  // b128 broadcast
      FMA4(a4.x, 0) FMA4(a4.y, 1) FMA4(a4.z, 2) FMA4(a4.w, 3)
    }
  }
  float4 b1v = *(const float4*)&b1[d4];
  __syncthreads();  // all aT reads done before z overwrites the region
  #pragma unroll
  for (int jj = 0; jj < 4; ++jj) {
    float4 v = acc[jj];
    v.x = gelu_exact(v.x + b1v.x);
    v.y = gelu_exact(v.y + b1v.y);
    v.z = gelu_exact(v.z + b1v.z);
    v.w = gelu_exact(v.w + b1v.w);
    *(float4*)&s_a[(j4 + jj) * 260 + d4] = v;  // z, row-major pitch 260
  }
  __syncthreads();
  // phase 3: out[j][p] = z[j][:] . W2[:, p]; W2 from global (32 KB, L1-hot)
  int j = t >> 4, c = t & 15;
  float2 o = make_float2(0.f, 0.f);
  #pragma unroll 8
  for (int dd = 0; dd < 256; ++dd) {
    float zv = s_a[j * 260 + dd];  // 4-way broadcast per wave
    float2 w = *(const float2*)&W2[dd * 32 + c * 2];
    o.x = fmaf(zv, w.x, o.x);
    o.y = fmaf(zv, w.y, o.y);
  }
  float2 b2v = *(const float2*)&b2[c * 2];
  o.x += b2v.x; o.y += b2v.y;
  *(float2*)&out[(size_t)(tok0 + j) * 32 + c * 2] = o;
}

extern "C" void kernel_launch(void* const* d_in, const int* in_sizes, int n_in,
                              void* d_out, int out_size, void* d_ws, size_t ws_size,
                              hipStream_t stream) {
  const float* y    = (const float*)d_in[0];
  const float* Win  = (const float*)d_in[1];
  const float* bin_ = (const float*)d_in[2];
  const float* ng   = (const float*)d_in[3];
  const float* nb   = (const float*)d_in[4];
  const float* A    = (const float*)d_in[5];
  const float* WB   = (const float*)d_in[6];
  const float* WC   = (const float*)d_in[7];
  const float* qd   = (const float*)d_in[8];
  const float* pd   = (const float*)d_in[9];
  const float* nfg  = (const float*)d_in[10];
  const float* nfb  = (const float*)d_in[11];
  const float* W1   = (const float*)d_in[12];
  const float* b1   = (const float*)d_in[13];
  const float* W2   = (const float*)d_in[14];
  const float* b2   = (const float*)d_in[15];

  float* ws = (float*)d_ws;
  float* hnbuf = ws;                          // NTOK*D = 4194304
  float* delta = ws + 4194304;                // NTOK
  float* Bm    = delta + NTOK;                // NTOK*NX
  float* Cm    = Bm + NTOK * NX;              // NTOK*NX
  float* muv   = Cm + NTOK * NX;              // NTOK
  float* irsv  = muv + NTOK;                  // NTOK
  float* Tbuf  = irsv + NTOK;                 // NBATCH*NCH = 1024
  float* At    = Tbuf + NBATCH * NCH;         // 4096
  float* Wbct  = At + D * NX;                 // 8192
  float* EX    = Wbct + D * 32;               // 1024*4096 = 4M floats (16 MB)

  k0_prep<<<48, 256, 0, stream>>>(A, WB, WC, At, Wbct);
  k1a_front_scan<<<NTOK / CL, 256, 0, stream>>>(y, Win, bin_, ng, nb, Wbct,
                                                qd, pd, At, hnbuf, delta, Bm,
                                                Cm, muv, irsv, EX, Tbuf);
  k2b_chunkscan<<<NBATCH * 16, 256, 0, stream>>>(At, Tbuf, EX);
  k2cd_scan_mlp<<<NTOK / CL, 256, 0, stream>>>(hnbuf, delta, Bm, Cm, At, EX,
                                               muv, irsv, ng, nb, nfg, nfb,
                                               W1, b1, W2, b2, (float*)d_out);
}

// Round 15
// 260.750 us; speedup vs baseline: 1.2826x; 1.2826x over previous
//
#include <hip/hip_runtime.h>
#include <math.h>

#define D 256
#define NX 16
#define L 2048
#define NBATCH 8
#define NTOK (NBATCH * L)
#define CL 32
#define NCH (L / CL)  // 64
#define LOG2E 1.44269504088896340736f

typedef float native_f4 __attribute__((ext_vector_type(4)));

__device__ __forceinline__ void nts4(float4* p, float4 v) {
  native_f4 nv = {v.x, v.y, v.z, v.w};
  __builtin_nontemporal_store(nv, (native_f4*)p);
}
__device__ __forceinline__ float4 ntl4(const float4* p) {
  native_f4 nv = __builtin_nontemporal_load((const native_f4*)p);
  return make_float4(nv.x, nv.y, nv.z, nv.w);
}
__device__ __forceinline__ void nts1(float* p, float v) {
  __builtin_nontemporal_store(v, p);
}
__device__ __forceinline__ float ntl1(const float* p) {
  return __builtin_nontemporal_load(p);
}

// ---------------- K0: At[n][d] = A[d][n]*LOG2E ; Wbct[d][c] = [WB;WC]^T -----
__global__ __launch_bounds__(256) void k0_prep(const float* __restrict__ A,
                                               const float* __restrict__ WB,
                                               const float* __restrict__ WC,
                                               float* __restrict__ At,
                                               float* __restrict__ Wbct) {
  int i = blockIdx.x * 256 + threadIdx.x;  // 12288 total
  if (i < 4096) {
    int d = i >> 4, n = i & 15;
    At[n * D + d] = A[i] * LOG2E;
  } else {
    int j = i - 4096;  // 8192
    int d = j >> 5, c = j & 31;
    Wbct[j] = (c < 16) ? WB[c * D + d] : WC[(c - 16) * D + d];
  }
}

// ---------------- K1a: front end + local chunk scan (NT streaming I/O) ------
__global__ __launch_bounds__(256) void k1a_front_scan(
    const float* __restrict__ y, const float* __restrict__ Win,
    const float* __restrict__ bin_, const float* __restrict__ ng,
    const float* __restrict__ nb, const float* __restrict__ Wbct,
    const float* __restrict__ qd, const float* __restrict__ pd,
    const float* __restrict__ At,
    float* __restrict__ hn, float* __restrict__ delta,
    float* __restrict__ Bm, float* __restrict__ Cm,
    float* __restrict__ muv, float* __restrict__ irsv,
    float* __restrict__ EX, float* __restrict__ T) {
  __shared__ float sy[32][32];
  __shared__ float sh[32][260];   // hn tile, pitch 260
  __shared__ float sB[32][NX];
  __shared__ float sdelta[32];
  int t = threadIdx.x;
  int tok0 = blockIdx.x * 32;
  {
    const float4* src = (const float4*)(y + (size_t)tok0 * 32);
    ((float4*)sy)[t] = ntl4(src + t);  // y read once -> NT
  }
  __syncthreads();
  int dcol = t & 63;
  int jrow = t >> 6;
  int d4 = dcol * 4;
  float4 bv = ((const float4*)bin_)[dcol];
  float4 acc[8];
  #pragma unroll
  for (int jj = 0; jj < 8; ++jj) acc[jj] = bv;
  const float4* Win4 = (const float4*)Win;
  #pragma unroll
  for (int k = 0; k < 32; ++k) {
    float4 wv = Win4[k * 64 + dcol];
    #pragma unroll
    for (int jj = 0; jj < 8; ++jj) {
      float av = sy[jrow * 8 + jj][k];
      acc[jj].x = fmaf(av, wv.x, acc[jj].x);
      acc[jj].y = fmaf(av, wv.y, acc[jj].y);
      acc[jj].z = fmaf(av, wv.z, acc[jj].z);
      acc[jj].w = fmaf(av, wv.w, acc[jj].w);
    }
  }
  float4 g4 = ((const float4*)ng)[dcol];
  float4 nb4 = ((const float4*)nb)[dcol];
  float4 q4 = ((const float4*)qd)[dcol];
  float pd0 = pd[0];
  #pragma unroll
  for (int jj = 0; jj < 8; ++jj) {
    int j = jrow * 8 + jj;
    int tok = tok0 + j;
    float4 a = acc[jj];
    float s1 = a.x + a.y + a.z + a.w;
    float s2 = a.x * a.x + a.y * a.y + a.z * a.z + a.w * a.w;
    #pragma unroll
    for (int off = 1; off < 64; off <<= 1) {
      s1 += __shfl_xor(s1, off);
      s2 += __shfl_xor(s2, off);
    }
    float mu = s1 * (1.f / D);
    float var = s2 * (1.f / D) - mu * mu;
    float rstd = rsqrtf(var + 1e-5f);
    if (dcol == 0) { nts1(&muv[tok], mu); nts1(&irsv[tok], sqrtf(var + 1e-5f)); }
    float4 v4;
    v4.x = (a.x - mu) * rstd * g4.x + nb4.x;
    v4.y = (a.y - mu) * rstd * g4.y + nb4.y;
    v4.z = (a.z - mu) * rstd * g4.z + nb4.z;
    v4.w = (a.w - mu) * rstd * g4.w + nb4.w;
    nts4((float4*)(hn + (size_t)tok * D) + dcol, v4);  // hn streamed -> NT
    *(float4*)&sh[j][d4] = v4;
    float dd = v4.x * q4.x + v4.y * q4.y + v4.z * q4.z + v4.w * q4.w;
    #pragma unroll
    for (int off = 1; off < 64; off <<= 1) dd += __shfl_xor(dd, off);
    if (dcol == 0) {
      float xx = pd0 + dd;
      float dv = (xx > 20.f) ? xx : log1pf(expf(xx));
      nts1(&delta[tok], dv);
      sdelta[j] = dv;
    }
  }
  __syncthreads();
  if (t < 32) {
    float v = sdelta[t];
    #pragma unroll
    for (int off = 1; off < 32; off <<= 1) v += __shfl_xor(v, off);
    if (t == 0) T[blockIdx.x] = v;
  }
  // Phase C: [Bm|Cm] = sh @ Wbct
  int col4 = t & 7;
  int j = t >> 3;
  const float4* W4 = (const float4*)Wbct;
  float4 o = make_float4(0.f, 0.f, 0.f, 0.f);
  #pragma unroll 8
  for (int d = 0; d < 256; ++d) {
    float av = sh[j][d];
    float4 w = W4[d * 8 + col4];
    o.x = fmaf(av, w.x, o.x);
    o.y = fmaf(av, w.y, o.y);
    o.z = fmaf(av, w.z, o.z);
    o.w = fmaf(av, w.w, o.w);
  }
  int tokj = tok0 + j;
  if (col4 < 4) {
    nts4((float4*)(Bm + (size_t)tokj * NX) + col4, o);
    *(float4*)&sB[j][col4 * 4] = o;
  } else {
    nts4((float4*)(Cm + (size_t)tokj * NX) + (col4 - 4), o);
  }
  __syncthreads();
  // local scan, zero init
  float a16[16];
  #pragma unroll
  for (int n = 0; n < 16; ++n) a16[n] = At[n * D + t];
  float x16[16];
  #pragma unroll
  for (int n = 0; n < 16; ++n) x16[n] = 0.f;
  for (int lo = 0; lo < CL; ++lo) {
    float dlt = sdelta[lo];
    float du = dlt * sh[lo][t];
    #pragma unroll
    for (int n = 0; n < 16; ++n)
      x16[n] = fmaf(exp2f(dlt * a16[n]), x16[n], du * sB[lo][n]);
  }
  size_t exbase = (size_t)blockIdx.x * (NX * D) + t;
  #pragma unroll
  for (int n = 0; n < 16; ++n) nts1(&EX[exbase + n * D], x16[n]);  // NT
}

// ---------------- K2b: chunk-level scan (NT on EX) --------------------------
__global__ __launch_bounds__(256) void k2b_chunkscan(
    const float* __restrict__ At, const float* __restrict__ T,
    float* __restrict__ EX) {
  __shared__ float sT[NCH];
  int b = blockIdx.x >> 4;
  int rem = ((blockIdx.x & 15) << 8) | threadIdx.x;  // n*D + d
  if (threadIdx.x < NCH) sT[threadIdx.x] = T[b * NCH + threadIdx.x];
  __syncthreads();
  float A2 = At[rem];
  size_t base = ((size_t)b << 18) + rem;
  float eq[4];
  #pragma unroll
  for (int j = 0; j < 4; ++j) eq[j] = ntl1(&EX[base + ((size_t)j << 12)]);
  float x = 0.f;
  #pragma unroll 4
  for (int c = 0; c < NCH; ++c) {
    float e = eq[c & 3];
    if (c + 4 < NCH) eq[c & 3] = ntl1(&EX[base + ((size_t)(c + 4) << 12)]);
    nts1(&EX[base + ((size_t)c << 12)], x);
    x = fmaf(exp2f(sT[c] * A2), x, e);
  }
}

__device__ __forceinline__ float gelu_exact(float x) {
  return 0.5f * x * (1.f + erff(x * 0.70710678118654752440f));
}

#define FMA4(AV, JJ)                          \
  acc[JJ].x = fmaf(AV, w.x, acc[JJ].x);       \
  acc[JJ].y = fmaf(AV, w.y, acc[JJ].y);       \
  acc[JJ].z = fmaf(AV, w.z, acc[JJ].z);       \
  acc[JJ].w = fmaf(AV, w.w, acc[JJ].w);

// ---------------- K2cd: scan + LN2 + MLP (NT streaming reads) ---------------
__global__ __launch_bounds__(256) void k2cd_scan_mlp(
    const float* __restrict__ hn, const float* __restrict__ delta,
    const float* __restrict__ Bm, const float* __restrict__ Cm,
    const float* __restrict__ At, const float* __restrict__ EX,
    const float* __restrict__ muv, const float* __restrict__ irsv,
    const float* __restrict__ ng, const float* __restrict__ nb,
    const float* __restrict__ nfg, const float* __restrict__ nfb,
    const float* __restrict__ W1, const float* __restrict__ b1,
    const float* __restrict__ W2, const float* __restrict__ b2,
    float* __restrict__ out) {
  __shared__ float s_a[256 * 36];   // aT[d][tok] (36.9 KB); later z[32][260]
  __shared__ float s_w[32 * 256];   // W1 k-tiles, then W2 (32 KB)
  __shared__ float sB[32][NX];
  __shared__ float sC[32][NX];
  __shared__ float sdelta[32];
  __shared__ float smu[32];
  __shared__ float sirs[32];
  int t = threadIdx.x;
  int tok0 = blockIdx.x * 32;
  size_t tokbase = (size_t)tok0;
  if (t < 32) {
    sdelta[t] = ntl1(&delta[tokbase + t]);
    smu[t] = ntl1(&muv[tokbase + t]);
    sirs[t] = ntl1(&irsv[tokbase + t]);
  }
  for (int i = t; i < 32 * NX; i += 256) {
    ((float*)sB)[i] = ntl1(&Bm[tokbase * NX + i]);
    ((float*)sC)[i] = ntl1(&Cm[tokbase * NX + i]);
  }
  float a16[16], x16[16];
  size_t exbase = (size_t)blockIdx.x * (NX * D) + t;
  #pragma unroll
  for (int n = 0; n < 16; ++n) {
    a16[n] = At[n * D + t];
    x16[n] = ntl1(&EX[exbase + n * D]);
  }
  float nb_d = nb[t];
  float invg = 1.0f / ng[t];
  __syncthreads();
  // fixup scan with true entering state -> transposed tile aT[d][lo]
  for (int lo = 0; lo < CL; ++lo) {
    float hv = ntl1(&hn[(tokbase + lo) * D + t]);  // streamed once -> NT
    float dlt = sdelta[lo];
    float du = dlt * hv;
    float p = 0.f;
    #pragma unroll
    for (int n = 0; n < 16; ++n) {
      x16[n] = fmaf(exp2f(dlt * a16[n]), x16[n], du * sB[lo][n]);
      p = fmaf(x16[n], sC[lo][n], p);
    }
    float h = fmaf((hv - nb_d) * invg, sirs[lo], smu[lo]);
    s_a[t * 36 + lo] = h + p;
  }
  __syncthreads();
  int dcol = t & 63, jrow = t >> 6;
  int d4 = dcol * 4, j8 = jrow * 8;
  // LN2 over aT columns
  {
    float g0 = nfg[dcol], g1 = nfg[dcol + 64], g2 = nfg[dcol + 128], g3 = nfg[dcol + 192];
    float c0 = nfb[dcol], c1 = nfb[dcol + 64], c2 = nfb[dcol + 128], c3 = nfb[dcol + 192];
    for (int jj = 0; jj < 8; ++jj) {
      int lo = j8 + jj;
      float v0 = s_a[dcol * 36 + lo];
      float v1 = s_a[(dcol + 64) * 36 + lo];
      float v2 = s_a[(dcol + 128) * 36 + lo];
      float v3 = s_a[(dcol + 192) * 36 + lo];
      float s1 = v0 + v1 + v2 + v3;
      float s2 = v0 * v0 + v1 * v1 + v2 * v2 + v3 * v3;
      #pragma unroll
      for (int off = 1; off < 64; off <<= 1) {
        s1 += __shfl_xor(s1, off);
        s2 += __shfl_xor(s2, off);
      }
      float mu2 = s1 * (1.f / D);
      float var2 = s2 * (1.f / D) - mu2 * mu2;
      float rstd2 = rsqrtf(var2 + 1e-5f);
      s_a[dcol * 36 + lo]         = (v0 - mu2) * rstd2 * g0 + c0;
      s_a[(dcol + 64) * 36 + lo]  = (v1 - mu2) * rstd2 * g1 + c1;
      s_a[(dcol + 128) * 36 + lo] = (v2 - mu2) * rstd2 * g2 + c2;
      s_a[(dcol + 192) * 36 + lo] = (v3 - mu2) * rstd2 * g3 + c3;
    }
  }
  // MLP W1 loop: a-operand = 2 wave-uniform b128 per k from aT
  float4 acc[8];
  #pragma unroll
  for (int jj = 0; jj < 8; ++jj) acc[jj] = make_float4(0.f, 0.f, 0.f, 0.f);
  for (int kb = 0; kb < 256; kb += 32) {
    __syncthreads();
    {
      const float4* wsrc = (const float4*)(W1 + kb * D);
      float4* wdst = (float4*)s_w;
      for (int i = t; i < 2048; i += 256) wdst[i] = wsrc[i];
    }
    __syncthreads();
    #pragma unroll 8
    for (int k = 0; k < 32; ++k) {
      float4 w = *(float4*)&s_w[k * D + d4];
      float4 alo = *(float4*)&s_a[(kb + k) * 36 + j8];
      float4 ahi = *(float4*)&s_a[(kb + k) * 36 + j8 + 4];
      FMA4(alo.x, 0) FMA4(alo.y, 1) FMA4(alo.z, 2) FMA4(alo.w, 3)
      FMA4(ahi.x, 4) FMA4(ahi.y, 5) FMA4(ahi.z, 6) FMA4(ahi.w, 7)
    }
  }
  float4 b1v = *(const float4*)&b1[d4];
  __syncthreads();
  #pragma unroll
  for (int jj = 0; jj < 8; ++jj) {
    float4 v = acc[jj];
    v.x = gelu_exact(v.x + b1v.x);
    v.y = gelu_exact(v.y + b1v.y);
    v.z = gelu_exact(v.z + b1v.z);
    v.w = gelu_exact(v.w + b1v.w);
    *(float4*)&s_a[(j8 + jj) * 260 + d4] = v;  // z, row-major pitch 260
  }
  {
    const float4* w2s = (const float4*)W2;
    float4* wdst = (float4*)s_w;
    for (int i = t; i < 2048; i += 256) wdst[i] = w2s[i];
  }
  __syncthreads();
  int j = t >> 3, p4 = (t & 7) * 4;
  float4 o = make_float4(0.f, 0.f, 0.f, 0.f);
  for (int dd = 0; dd < 256; ++dd) {
    float zv = s_a[j * 260 + dd];
    float4 w = *(float4*)&s_w[dd * 32 + p4];
    o.x = fmaf(zv, w.x, o.x);
    o.y = fmaf(zv, w.y, o.y);
    o.z = fmaf(zv, w.z, o.z);
    o.w = fmaf(zv, w.w, o.w);
  }
  float4 b2v = *(const float4*)&b2[p4];
  o.x += b2v.x; o.y += b2v.y; o.z += b2v.z; o.w += b2v.w;
  nts4((float4*)&out[(size_t)(tok0 + j) * 32 + p4], o);
}

extern "C" void kernel_launch(void* const* d_in, const int* in_sizes, int n_in,
                              void* d_out, int out_size, void* d_ws, size_t ws_size,
                              hipStream_t stream) {
  const float* y    = (const float*)d_in[0];
  const float* Win  = (const float*)d_in[1];
  const float* bin_ = (const float*)d_in[2];
  const float* ng   = (const float*)d_in[3];
  const float* nb   = (const float*)d_in[4];
  const float* A    = (const float*)d_in[5];
  const float* WB   = (const float*)d_in[6];
  const float* WC   = (const float*)d_in[7];
  const float* qd   = (const float*)d_in[8];
  const float* pd   = (const float*)d_in[9];
  const float* nfg  = (const float*)d_in[10];
  const float* nfb  = (const float*)d_in[11];
  const float* W1   = (const float*)d_in[12];
  const float* b1   = (const float*)d_in[13];
  const float* W2   = (const float*)d_in[14];
  const float* b2   = (const float*)d_in[15];

  float* ws = (float*)d_ws;
  float* hnbuf = ws;                          // NTOK*D
  float* delta = ws + 4194304;                // NTOK
  float* Bm    = delta + NTOK;                // NTOK*NX
  float* Cm    = Bm + NTOK * NX;              // NTOK*NX
  float* muv   = Cm + NTOK * NX;              // NTOK
  float* irsv  = muv + NTOK;                  // NTOK
  float* Tbuf  = irsv + NTOK;                 // 512
  float* At    = Tbuf + NBATCH * NCH;         // 4096
  float* Wbct  = At + D * NX;                 // 8192
  float* EX    = Wbct + D * 32;               // 512*4096 = 2M floats

  k0_prep<<<48, 256, 0, stream>>>(A, WB, WC, At, Wbct);
  k1a_front_scan<<<NTOK / 32, 256, 0, stream>>>(y, Win, bin_, ng, nb, Wbct,
                                                qd, pd, At, hnbuf, delta, Bm,
                                                Cm, muv, irsv, EX, Tbuf);
  k2b_chunkscan<<<NBATCH * 16, 256, 0, stream>>>(At, Tbuf, EX);
  k2cd_scan_mlp<<<NTOK / 32, 256, 0, stream>>>(hnbuf, delta, Bm, Cm, At, EX,
                                               muv, irsv, ng, nb, nfg, nfb,
                                               W1, b1, W2, b2, (float*)d_out);
}